// Round 1
// baseline (141.632 us; speedup 1.0000x reference)
//
#include <hip/hip_runtime.h>

#define SLEN 8192
#define DIN  512
#define NSPLIT 4
#define KITERS 32   // (8192/NSPLIT)/64

typedef short bf16x8 __attribute__((ext_vector_type(8)));
typedef float f32x4  __attribute__((ext_vector_type(4)));
typedef unsigned int u32x4 __attribute__((ext_vector_type(4)));

__device__ __forceinline__ unsigned short f2bf(float f) {
  unsigned int u = __float_as_uint(f);
  u += 0x7FFFu + ((u >> 16) & 1u);           // RNE
  return (unsigned short)(u >> 16);
}
__device__ __forceinline__ float bf2f(unsigned short h) {
  return __uint_as_float(((unsigned int)h) << 16);
}

#define MFMA16(a, b, c) __builtin_amdgcn_mfma_f32_16x16x32_bf16((a), (b), (c), 0, 0, 0)

// XOR swizzle for [row][128B] LDS tiles: flips bits 4-6 -> conflict-free-ish ds_read_b128
__device__ __forceinline__ int SW(int row, int off) {
  return row * 128 + (off ^ ((row & 7) << 4));
}

// ---------------- A: split x (f32) -> xh, xl (bf16) ----------------
__global__ __launch_bounds__(256) void k_splitx(const float* __restrict__ x,
                                                unsigned short* __restrict__ xh,
                                                unsigned short* __restrict__ xl) {
  int i = blockIdx.x * 256 + threadIdx.x;    // float4 index, 1048576 total
  float4 v = reinterpret_cast<const float4*>(x)[i];
  float vv[4] = {v.x, v.y, v.z, v.w};
  unsigned long long ph = 0ull, pl = 0ull;
  for (int j = 0; j < 4; ++j) {
    unsigned short h = f2bf(vv[j]);
    unsigned short l = f2bf(vv[j] - bf2f(h));
    ph |= ((unsigned long long)h) << (16 * j);
    pl |= ((unsigned long long)l) << (16 * j);
  }
  reinterpret_cast<unsigned long long*>(xh)[i] = ph;
  reinterpret_cast<unsigned long long*>(xl)[i] = pl;
}

// ------- B: split + transpose W -> Wt[n][k], n: 0-63 Q(scaled), 64-127 K, 128-191 V -------
__global__ __launch_bounds__(256) void k_splitw(const float* __restrict__ Wq,
                                                const float* __restrict__ Wk,
                                                const float* __restrict__ Wv,
                                                unsigned short* __restrict__ Wth,
                                                unsigned short* __restrict__ Wtl) {
  int idx = blockIdx.x * 256 + threadIdx.x;  // n*512 + k, 98304 total
  int n = idx >> 9, k = idx & 511;
  float w;
  if (n < 64)       w = Wq[k * 64 + n] * 0.18033688011112042f;  // log2(e)/8 folded in
  else if (n < 128) w = Wk[k * 64 + (n - 64)];
  else              w = Wv[k * 64 + (n - 128)];
  unsigned short h = f2bf(w);
  Wth[idx] = h;
  Wtl[idx] = f2bf(w - bf2f(h));
}

// ---------------- C: QKV = x @ [Wq|Wk|Wv] via 3-term split MFMA ----------------
__global__ __launch_bounds__(256) void k_qkv(const unsigned short* __restrict__ xh,
                                             const unsigned short* __restrict__ xl,
                                             const unsigned short* __restrict__ Wth,
                                             const unsigned short* __restrict__ Wtl,
                                             unsigned short* __restrict__ Qh,
                                             unsigned short* __restrict__ Ql,
                                             unsigned short* __restrict__ Kh,
                                             unsigned short* __restrict__ Kl,
                                             unsigned short* __restrict__ Vt) {
  const int tid = threadIdx.x;
  const int wave = tid >> 6, lane = tid & 63;
  const int c = lane & 15, g = lane >> 4;
  const int mbase = blockIdx.x * 64;       // 128 m-tiles
  const int nt0 = blockIdx.y * 6;          // 2 n-splits of 6 ntiles

  const int rowA = mbase + wave * 16 + c;  // A-operand row = lane&15
  f32x4 acc[6];
  for (int j = 0; j < 6; ++j) acc[j] = (f32x4){0.f, 0.f, 0.f, 0.f};

  for (int k0 = 0; k0 < DIN; k0 += 32) {
    bf16x8 ah = *reinterpret_cast<const bf16x8*>(&xh[rowA * DIN + k0 + g * 8]);
    bf16x8 al = *reinterpret_cast<const bf16x8*>(&xl[rowA * DIN + k0 + g * 8]);
    for (int j = 0; j < 6; ++j) {
      int ncol = (nt0 + j) * 16 + c;       // B-operand col = lane&15
      bf16x8 bh = *reinterpret_cast<const bf16x8*>(&Wth[ncol * DIN + k0 + g * 8]);
      bf16x8 bl = *reinterpret_cast<const bf16x8*>(&Wtl[ncol * DIN + k0 + g * 8]);
      acc[j] = MFMA16(ah, bh, acc[j]);
      acc[j] = MFMA16(ah, bl, acc[j]);
      acc[j] = MFMA16(al, bh, acc[j]);
    }
  }
  // C layout: col=lane&15, row=(lane>>4)*4+r
  for (int j = 0; j < 6; ++j) {
    int nt = nt0 + j;
    for (int r = 0; r < 4; ++r) {
      int Rrow = mbase + wave * 16 + g * 4 + r;
      float v = acc[j][r];
      unsigned short h = f2bf(v);
      unsigned short lo = f2bf(v - bf2f(h));
      if (nt < 4) {
        Qh[Rrow * 64 + nt * 16 + c] = h;
        Ql[Rrow * 64 + nt * 16 + c] = lo;
      } else if (nt < 8) {
        Kh[Rrow * 64 + (nt - 4) * 16 + c] = h;
        Kl[Rrow * 64 + (nt - 4) * 16 + c] = lo;
      } else {
        Vt[((nt - 8) * 16 + c) * SLEN + Rrow] = h;   // V transposed [64][8192]
      }
    }
  }
}

// ---------------- D: flash attention, K-split partials ----------------
__global__ __launch_bounds__(256) void k_flash(const unsigned short* __restrict__ Qh,
                                               const unsigned short* __restrict__ Ql,
                                               const unsigned short* __restrict__ Kh,
                                               const unsigned short* __restrict__ Kl,
                                               const unsigned short* __restrict__ Vt,
                                               float* __restrict__ pO,
                                               float* __restrict__ pML) {
  __shared__ __align__(16) unsigned char smem[3 * 8192 + 4 * 2048];
  const int tid = threadIdx.x;
  const int wave = tid >> 6, lane = tid & 63;
  const int c = lane & 15, g = lane >> 4;
  const int qtile = blockIdx.x;   // 0..127
  const int ks = blockIdx.y;      // 0..NSPLIT-1
  unsigned char* KH = smem;
  unsigned char* KL = smem + 8192;
  unsigned char* VT = smem + 16384;
  unsigned char* PW = smem + 24576 + wave * 2048;

  // Q fragments (A-operand: row=lane&15, k=(lane>>4)*8+j), scores pre-scaled by log2e/8
  const int qrowA = qtile * 64 + wave * 16 + c;
  bf16x8 qh[2], ql[2];
  for (int kk = 0; kk < 2; ++kk) {
    qh[kk] = *reinterpret_cast<const bf16x8*>(&Qh[qrowA * 64 + kk * 32 + g * 8]);
    ql[kk] = *reinterpret_cast<const bf16x8*>(&Ql[qrowA * 64 + kk * 32 + g * 8]);
  }

  f32x4 o[4];
  for (int d = 0; d < 4; ++d) o[d] = (f32x4){0.f, 0.f, 0.f, 0.f};
  float m_run[4] = {-1e30f, -1e30f, -1e30f, -1e30f};
  float l_run[4] = {0.f, 0.f, 0.f, 0.f};

  for (int it = 0; it < KITERS; ++it) {
    const int kbase = ks * (SLEN / NSPLIT) + it * 64;
    __syncthreads();
    // stage Kh/Kl/Vt tiles [64][64] bf16, swizzled
    for (int u = 0; u < 2; ++u) {
      int unit = tid + u * 256;
      int row = unit >> 3, seg = unit & 7;
      u32x4 a = *reinterpret_cast<const u32x4*>(&Kh[(kbase + row) * 64 + seg * 8]);
      *reinterpret_cast<u32x4*>(&KH[SW(row, seg * 16)]) = a;
      u32x4 b = *reinterpret_cast<const u32x4*>(&Kl[(kbase + row) * 64 + seg * 8]);
      *reinterpret_cast<u32x4*>(&KL[SW(row, seg * 16)]) = b;
      u32x4 vv = *reinterpret_cast<const u32x4*>(&Vt[row * SLEN + kbase + seg * 8]);
      *reinterpret_cast<u32x4*>(&VT[SW(row, seg * 16)]) = vv;
    }
    __syncthreads();

    // S = Q·K^T (3-term split), 4 k-col tiles of 16
    f32x4 s[4];
    for (int t = 0; t < 4; ++t) s[t] = (f32x4){0.f, 0.f, 0.f, 0.f};
    for (int t = 0; t < 4; ++t) {
      for (int kk = 0; kk < 2; ++kk) {
        bf16x8 bh = *reinterpret_cast<const bf16x8*>(&KH[SW(t * 16 + c, kk * 64 + g * 16)]);
        bf16x8 bl = *reinterpret_cast<const bf16x8*>(&KL[SW(t * 16 + c, kk * 64 + g * 16)]);
        s[t] = MFMA16(qh[kk], bh, s[t]);
        s[t] = MFMA16(qh[kk], bl, s[t]);
        s[t] = MFMA16(ql[kk], bh, s[t]);
      }
    }

    // online softmax in log2 domain; row = g*4+r, col = lane&15 (+16t)
    float alpha[4];
    for (int r = 0; r < 4; ++r) {
      float mt = fmaxf(fmaxf(s[0][r], s[1][r]), fmaxf(s[2][r], s[3][r]));
      mt = fmaxf(mt, __shfl_xor(mt, 1));
      mt = fmaxf(mt, __shfl_xor(mt, 2));
      mt = fmaxf(mt, __shfl_xor(mt, 4));
      mt = fmaxf(mt, __shfl_xor(mt, 8));
      float mnew = fmaxf(m_run[r], mt);
      alpha[r] = exp2f(m_run[r] - mnew);
      m_run[r] = mnew;
      float rs = 0.f;
      for (int t = 0; t < 4; ++t) {
        float p = exp2f(s[t][r] - mnew);
        s[t][r] = p;
        rs += p;
      }
      rs += __shfl_xor(rs, 1);
      rs += __shfl_xor(rs, 2);
      rs += __shfl_xor(rs, 4);
      rs += __shfl_xor(rs, 8);
      l_run[r] = l_run[r] * alpha[r] + rs;
      for (int d = 0; d < 4; ++d) o[d][r] *= alpha[r];
    }

    // bounce P through per-wave LDS to get PV A-operand layout (wave-local, no barrier)
    for (int t = 0; t < 4; ++t)
      for (int r = 0; r < 4; ++r) {
        int rw = g * 4 + r;
        *reinterpret_cast<unsigned short*>(&PW[SW(rw, (t * 16 + c) * 2)]) = f2bf(s[t][r]);
      }
    bf16x8 pa0 = *reinterpret_cast<const bf16x8*>(&PW[SW(c, g * 16)]);
    bf16x8 pa1 = *reinterpret_cast<const bf16x8*>(&PW[SW(c, 64 + g * 16)]);
    for (int d = 0; d < 4; ++d) {
      bf16x8 v0 = *reinterpret_cast<const bf16x8*>(&VT[SW(d * 16 + c, g * 16)]);
      bf16x8 v1 = *reinterpret_cast<const bf16x8*>(&VT[SW(d * 16 + c, 64 + g * 16)]);
      o[d] = MFMA16(pa0, v0, o[d]);
      o[d] = MFMA16(pa1, v1, o[d]);
    }
  }

  // write partials (undivided O, running m and l in log2 domain)
  const int R0 = qtile * 64 + wave * 16;
  for (int d = 0; d < 4; ++d)
    for (int r = 0; r < 4; ++r)
      pO[(ks * SLEN + R0 + g * 4 + r) * 64 + d * 16 + c] = o[d][r];
  if (c == 0)
    for (int r = 0; r < 4; ++r) {
      pML[(ks * SLEN + R0 + g * 4 + r) * 2 + 0] = m_run[r];
      pML[(ks * SLEN + R0 + g * 4 + r) * 2 + 1] = l_run[r];
    }
}

// ---------------- E: merge K-split partials ----------------
__global__ __launch_bounds__(256) void k_merge(const float* __restrict__ pO,
                                               const float* __restrict__ pML,
                                               float* __restrict__ out) {
  int idx = blockIdx.x * 256 + threadIdx.x;  // 524288
  int row = idx >> 6, d = idx & 63;
  float M = -1e30f;
  for (int s = 0; s < NSPLIT; ++s) M = fmaxf(M, pML[(s * SLEN + row) * 2 + 0]);
  float L = 0.f, O = 0.f;
  for (int s = 0; s < NSPLIT; ++s) {
    float ms = pML[(s * SLEN + row) * 2 + 0];
    float ls = pML[(s * SLEN + row) * 2 + 1];
    float w = exp2f(ms - M);
    L += ls * w;
    O += pO[(s * SLEN + row) * 64 + d] * w;
  }
  out[idx] = O / L;
}

extern "C" void kernel_launch(void* const* d_in, const int* in_sizes, int n_in,
                              void* d_out, int out_size, void* d_ws, size_t ws_size,
                              hipStream_t stream) {
  const float* x  = (const float*)d_in[0];
  const float* Wq = (const float*)d_in[1];
  const float* Wk = (const float*)d_in[2];
  const float* Wv = (const float*)d_in[3];
  float* out = (float*)d_out;

  char* ws = (char*)d_ws;
  unsigned short* xh  = (unsigned short*)ws;                       // 8.39 MB
  unsigned short* xl  = xh + SLEN * DIN;                           // 8.39 MB
  unsigned short* Wth = xl + SLEN * DIN;                           // 196 KB
  unsigned short* Wtl = Wth + 192 * DIN;                           // 196 KB
  unsigned short* Qh  = Wtl + 192 * DIN;                           // 1 MB each
  unsigned short* Ql  = Qh + SLEN * 64;
  unsigned short* Kh  = Ql + SLEN * 64;
  unsigned short* Kl  = Kh + SLEN * 64;
  unsigned short* Vt  = Kl + SLEN * 64;
  // partials alias xh/xl (consumed before k_flash writes them)
  float* pO  = (float*)ws;                                         // 8.39 MB
  float* pML = (float*)(ws + (size_t)SLEN * DIN * 2);              // 256 KB

  k_splitx<<<dim3(4096), dim3(256), 0, stream>>>(x, xh, xl);
  k_splitw<<<dim3(384), dim3(256), 0, stream>>>(Wq, Wk, Wv, Wth, Wtl);
  k_qkv<<<dim3(128, 2), dim3(256), 0, stream>>>(xh, xl, Wth, Wtl, Qh, Ql, Kh, Kl, Vt);
  k_flash<<<dim3(128, NSPLIT), dim3(256), 0, stream>>>(Qh, Ql, Kh, Kl, Vt, pO, pML);
  k_merge<<<dim3(2048), dim3(256), 0, stream>>>(pO, pML, out);
}

// Round 3
// 116.742 us; speedup vs baseline: 1.2132x; 1.2132x over previous
//
#include <hip/hip_runtime.h>

#define SLEN 8192
#define DIN  512
#define NSPLIT 8
#define KITERS 16   // (8192/NSPLIT)/64

typedef short bf16x8 __attribute__((ext_vector_type(8)));
typedef float f32x4  __attribute__((ext_vector_type(4)));
typedef unsigned int u32x4 __attribute__((ext_vector_type(4)));
typedef unsigned int u32x2 __attribute__((ext_vector_type(2)));

__device__ __forceinline__ unsigned short f2bf(float f) {
  unsigned int u = __float_as_uint(f);
  u += 0x7FFFu + ((u >> 16) & 1u);           // RNE
  return (unsigned short)(u >> 16);
}
__device__ __forceinline__ float bf2f(unsigned short h) {
  return __uint_as_float(((unsigned int)h) << 16);
}
__device__ __forceinline__ unsigned int cvtpk(float lo, float hi) {
  unsigned int r;
  asm volatile("v_cvt_pk_bf16_f32 %0, %1, %2" : "=v"(r) : "v"(lo), "v"(hi));
  return r;
}

#define MFMA16(a, b, c) __builtin_amdgcn_mfma_f32_16x16x32_bf16((a), (b), (c), 0, 0, 0)

// XOR swizzle for [row][128B] LDS tiles (K/V staging)
__device__ __forceinline__ int SW(int row, int off) {
  return row * 128 + (off ^ ((row & 7) << 4));
}

// ------- B: split + transpose W -> Wt[n][k], n: 0-63 Q(scaled), 64-127 K, 128-191 V -------
__global__ __launch_bounds__(256) void k_splitw(const float* __restrict__ Wq,
                                                const float* __restrict__ Wk,
                                                const float* __restrict__ Wv,
                                                unsigned short* __restrict__ Wth,
                                                unsigned short* __restrict__ Wtl) {
  int idx = blockIdx.x * 256 + threadIdx.x;  // n*512 + k, 98304 total
  int n = idx >> 9, k = idx & 511;
  float w;
  if (n < 64)       w = Wq[k * 64 + n] * 0.18033688011112042f;  // log2(e)/8 folded in
  else if (n < 128) w = Wk[k * 64 + (n - 64)];
  else              w = Wv[k * 64 + (n - 128)];
  unsigned short h = f2bf(w);
  Wth[idx] = h;
  Wtl[idx] = f2bf(w - bf2f(h));
}

// ---------------- C: partial QKV (K-split) = x @ [Wq|Wk|Wv], f32 partials ----------------
__global__ __launch_bounds__(256) void k_qkv(const float* __restrict__ x,
                                             const unsigned short* __restrict__ Wth,
                                             const unsigned short* __restrict__ Wtl,
                                             float* __restrict__ pQKV) {
  const int tid = threadIdx.x;
  const int wave = tid >> 6, lane = tid & 63;
  const int c = lane & 15, g = lane >> 4;
  const int mbase = blockIdx.x * 64;       // 128 m-tiles
  const int nt0 = blockIdx.y * 6;          // 2 n-splits of 6 ntiles
  const int ks = blockIdx.z;               // 2 K-splits of 256

  const int rowA = mbase + wave * 16 + c;  // A-operand row = lane&15
  f32x4 acc[6];
  for (int j = 0; j < 6; ++j) acc[j] = (f32x4){0.f, 0.f, 0.f, 0.f};

  for (int k0 = ks * 256; k0 < ks * 256 + 256; k0 += 32) {
    const float* xp = x + rowA * DIN + k0 + g * 8;
    float4 f0 = *reinterpret_cast<const float4*>(xp);
    float4 f1 = *reinterpret_cast<const float4*>(xp + 4);
    float fv[8] = {f0.x, f0.y, f0.z, f0.w, f1.x, f1.y, f1.z, f1.w};
    bf16x8 ah, al;
#pragma unroll
    for (int j = 0; j < 8; ++j) {
      unsigned short h = f2bf(fv[j]);
      ah[j] = (short)h;
      al[j] = (short)f2bf(fv[j] - bf2f(h));
    }
#pragma unroll
    for (int j = 0; j < 6; ++j) {
      int ncol = (nt0 + j) * 16 + c;       // B-operand col = lane&15
      bf16x8 bh = *reinterpret_cast<const bf16x8*>(&Wth[ncol * DIN + k0 + g * 8]);
      bf16x8 bl = *reinterpret_cast<const bf16x8*>(&Wtl[ncol * DIN + k0 + g * 8]);
      acc[j] = MFMA16(ah, bh, acc[j]);
      acc[j] = MFMA16(ah, bl, acc[j]);
      acc[j] = MFMA16(al, bh, acc[j]);
    }
  }
  // C layout: col=lane&15, row=(lane>>4)*4+r
  float* dst = pQKV + (size_t)ks * SLEN * 192;
#pragma unroll
  for (int j = 0; j < 6; ++j)
#pragma unroll
    for (int r = 0; r < 4; ++r)
      dst[(size_t)(mbase + wave * 16 + g * 4 + r) * 192 + (nt0 + j) * 16 + c] = acc[j][r];
}

// ---------------- C2: sum partials, split Q/K hi-lo ----------------
__global__ __launch_bounds__(256) void k_finqk(const float* __restrict__ pQKV,
                                               unsigned short* __restrict__ Qh,
                                               unsigned short* __restrict__ Ql,
                                               unsigned short* __restrict__ Kh,
                                               unsigned short* __restrict__ Kl) {
  int idx = blockIdx.x * 256 + threadIdx.x;  // 8192*128 -> 4096 blocks
  int row = idx >> 7, n = idx & 127;
  float v = pQKV[(size_t)row * 192 + n] + pQKV[(size_t)SLEN * 192 + (size_t)row * 192 + n];
  unsigned short h = f2bf(v);
  unsigned short lo = f2bf(v - bf2f(h));
  if (n < 64) { Qh[row * 64 + n] = h;        Ql[row * 64 + n] = lo; }
  else        { Kh[row * 64 + n - 64] = h;   Kl[row * 64 + n - 64] = lo; }
}

// ---------------- C3: sum partials, transpose V via LDS ----------------
__global__ __launch_bounds__(256) void k_finv(const float* __restrict__ pQKV,
                                              unsigned short* __restrict__ Vt) {
  __shared__ float t[64][65];
  const int b = blockIdx.x;  // 128 row-blocks of 64
#pragma unroll
  for (int i = 0; i < 16; ++i) {
    int idx = i * 256 + threadIdx.x;         // 4096 = 64x64
    int r_ = idx >> 6, n_ = idx & 63;
    size_t off = (size_t)(b * 64 + r_) * 192 + 128 + n_;
    t[r_][n_] = pQKV[off] + pQKV[(size_t)SLEN * 192 + off];
  }
  __syncthreads();
#pragma unroll
  for (int i = 0; i < 16; ++i) {
    int idx = i * 256 + threadIdx.x;
    int n_ = idx >> 6, r_ = idx & 63;
    Vt[(size_t)n_ * SLEN + b * 64 + r_] = f2bf(t[r_][n_]);
  }
}

// ---------------- D: flash attention, K-split partials ----------------
__global__ __launch_bounds__(256) void k_flash(const unsigned short* __restrict__ Qh,
                                               const unsigned short* __restrict__ Ql,
                                               const unsigned short* __restrict__ Kh,
                                               const unsigned short* __restrict__ Kl,
                                               const unsigned short* __restrict__ Vt,
                                               unsigned short* __restrict__ pOn,
                                               float* __restrict__ pML) {
  __shared__ __align__(16) unsigned char smem[3 * 8192 + 4 * 2048];
  const int tid = threadIdx.x;
  const int wave = tid >> 6, lane = tid & 63;
  const int c = lane & 15, g = lane >> 4;
  const int qtile = blockIdx.x;   // 0..127
  const int ks = blockIdx.y;      // 0..NSPLIT-1
  unsigned char* KH = smem;
  unsigned char* KL = smem + 8192;
  unsigned char* VT = smem + 16384;
  // per-wave P region, layout slot(q,k) = q + (k&3)*16 + (k>>2)*64 (bf16 elems)
  const unsigned pwBase = (unsigned)(uintptr_t)(smem + 24576 + wave * 2048);
  const unsigned pwW = pwBase + 2u * (g * 4 + (c & 3) * 16 + (c >> 2) * 64); // +512*t per t
  const unsigned pwR = pwBase + 8u * c + 256u * g;  // tr-read: natural 8B/lane + group block

  // Q fragments (A-operand: row=lane&15, k=(lane>>4)*8+j), scores pre-scaled by log2e/8
  const int qrowA = qtile * 64 + wave * 16 + c;
  bf16x8 qh[2], ql[2];
#pragma unroll
  for (int kk = 0; kk < 2; ++kk) {
    qh[kk] = *reinterpret_cast<const bf16x8*>(&Qh[qrowA * 64 + kk * 32 + g * 8]);
    ql[kk] = *reinterpret_cast<const bf16x8*>(&Ql[qrowA * 64 + kk * 32 + g * 8]);
  }

  bf16x8 ones8;
#pragma unroll
  for (int j = 0; j < 8; ++j) ones8[j] = (short)0x3F80;  // bf16 1.0

  f32x4 o[4];
  for (int d = 0; d < 4; ++d) o[d] = (f32x4){0.f, 0.f, 0.f, 0.f};
  float m_run[4] = {-1e30f, -1e30f, -1e30f, -1e30f};
  float l_run[4] = {0.f, 0.f, 0.f, 0.f};

  // staging prefetch registers
  u32x4 rA[2], rB[2], rC[2];
  auto LOADTILE = [&](int it) {
    const int kb = ks * (SLEN / NSPLIT) + it * 64;
#pragma unroll
    for (int u = 0; u < 2; ++u) {
      int unit = tid + u * 256;
      int row = unit >> 3, seg = unit & 7;
      rA[u] = *reinterpret_cast<const u32x4*>(&Kh[(kb + row) * 64 + seg * 8]);
      rB[u] = *reinterpret_cast<const u32x4*>(&Kl[(kb + row) * 64 + seg * 8]);
      rC[u] = *reinterpret_cast<const u32x4*>(&Vt[row * SLEN + kb + seg * 8]);
    }
  };

  LOADTILE(0);
  for (int it = 0; it < KITERS; ++it) {
    __syncthreads();
#pragma unroll
    for (int u = 0; u < 2; ++u) {
      int unit = tid + u * 256;
      int row = unit >> 3, seg = unit & 7;
      *reinterpret_cast<u32x4*>(&KH[SW(row, seg * 16)]) = rA[u];
      *reinterpret_cast<u32x4*>(&KL[SW(row, seg * 16)]) = rB[u];
      *reinterpret_cast<u32x4*>(&VT[SW(row, seg * 16)]) = rC[u];
    }
    __syncthreads();
    if (it + 1 < KITERS) LOADTILE(it + 1);   // loads fly during compute

    // S = Q·K^T (3-term split), 4 k-col tiles of 16
    f32x4 s[4];
#pragma unroll
    for (int t = 0; t < 4; ++t) s[t] = (f32x4){0.f, 0.f, 0.f, 0.f};
    __builtin_amdgcn_s_setprio(1);
#pragma unroll
    for (int t = 0; t < 4; ++t) {
#pragma unroll
      for (int kk = 0; kk < 2; ++kk) {
        bf16x8 bh = *reinterpret_cast<const bf16x8*>(&KH[SW(t * 16 + c, kk * 64 + g * 16)]);
        bf16x8 bl = *reinterpret_cast<const bf16x8*>(&KL[SW(t * 16 + c, kk * 64 + g * 16)]);
        s[t] = MFMA16(qh[kk], bh, s[t]);
        s[t] = MFMA16(qh[kk], bl, s[t]);
        s[t] = MFMA16(ql[kk], bh, s[t]);
      }
    }
    __builtin_amdgcn_s_setprio(0);

    // online softmax in log2 domain; row q = g*4+r, col k = t*16 + c
    float alpha[4];
#pragma unroll
    for (int r = 0; r < 4; ++r) {
      float mt = fmaxf(fmaxf(s[0][r], s[1][r]), fmaxf(s[2][r], s[3][r]));
      mt = fmaxf(mt, __shfl_xor(mt, 1));
      mt = fmaxf(mt, __shfl_xor(mt, 2));
      mt = fmaxf(mt, __shfl_xor(mt, 4));
      mt = fmaxf(mt, __shfl_xor(mt, 8));
      float mnew = fmaxf(m_run[r], mt);
      alpha[r] = exp2f(m_run[r] - mnew);
      m_run[r] = mnew;
#pragma unroll
      for (int t = 0; t < 4; ++t) s[t][r] = exp2f(s[t][r] - mnew);
#pragma unroll
      for (int d = 0; d < 4; ++d) o[d][r] *= alpha[r];
    }

    // P -> per-wave LDS (packed b64 writes); tr_b16 reads give PV A-fragments
#pragma unroll
    for (int t = 0; t < 4; ++t) {
      u32x2 w;
      w.x = cvtpk(s[t][0], s[t][1]);
      w.y = cvtpk(s[t][2], s[t][3]);
      if (t == 0) asm volatile("ds_write_b64 %0, %1"             :: "v"(pwW), "v"(w) : "memory");
      if (t == 1) asm volatile("ds_write_b64 %0, %1 offset:512"  :: "v"(pwW), "v"(w) : "memory");
      if (t == 2) asm volatile("ds_write_b64 %0, %1 offset:1024" :: "v"(pwW), "v"(w) : "memory");
      if (t == 3) asm volatile("ds_write_b64 %0, %1 offset:1536" :: "v"(pwW), "v"(w) : "memory");
    }
    u32x2 t00, t01, t10, t11;
    asm volatile("ds_read_b64_tr_b16 %0, %1"             : "=v"(t00) : "v"(pwR));
    asm volatile("ds_read_b64_tr_b16 %0, %1 offset:128"  : "=v"(t01) : "v"(pwR));
    asm volatile("ds_read_b64_tr_b16 %0, %1 offset:1024" : "=v"(t10) : "v"(pwR));
    asm volatile("ds_read_b64_tr_b16 %0, %1 offset:1152" : "=v"(t11) : "v"(pwR));
    asm volatile("s_waitcnt lgkmcnt(0)" ::: "memory");
    __builtin_amdgcn_sched_barrier(0);
    u32x4 pw0 = {t00.x, t00.y, t01.x, t01.y};
    u32x4 pw1 = {t10.x, t10.y, t11.x, t11.y};
    bf16x8 pa0 = *reinterpret_cast<bf16x8*>(&pw0);
    bf16x8 pa1 = *reinterpret_cast<bf16x8*>(&pw1);

    __builtin_amdgcn_s_setprio(1);
    // row-sums via MFMA with ones B-operand: rs[r] = sum_k P[q=g*4+r][k]
    f32x4 rs = (f32x4){0.f, 0.f, 0.f, 0.f};
    rs = MFMA16(pa0, ones8, rs);
    rs = MFMA16(pa1, ones8, rs);
#pragma unroll
    for (int d = 0; d < 4; ++d) {
      bf16x8 v0 = *reinterpret_cast<const bf16x8*>(&VT[SW(d * 16 + c, g * 16)]);
      bf16x8 v1 = *reinterpret_cast<const bf16x8*>(&VT[SW(d * 16 + c, 64 + g * 16)]);
      o[d] = MFMA16(pa0, v0, o[d]);
      o[d] = MFMA16(pa1, v1, o[d]);
    }
    __builtin_amdgcn_s_setprio(0);
#pragma unroll
    for (int r = 0; r < 4; ++r) l_run[r] = l_run[r] * alpha[r] + rs[r];
  }

  // write normalized partials (bf16) + (m,l) per row
  const int R0 = qtile * 64 + wave * 16;
  float inv[4];
#pragma unroll
  for (int r = 0; r < 4; ++r) inv[r] = 1.0f / l_run[r];
#pragma unroll
  for (int d = 0; d < 4; ++d)
#pragma unroll
    for (int r = 0; r < 4; ++r)
      pOn[((size_t)ks * SLEN + R0 + g * 4 + r) * 64 + d * 16 + c] = f2bf(o[d][r] * inv[r]);
  if (c == 0)
#pragma unroll
    for (int r = 0; r < 4; ++r) {
      pML[((size_t)ks * SLEN + R0 + g * 4 + r) * 2 + 0] = m_run[r];
      pML[((size_t)ks * SLEN + R0 + g * 4 + r) * 2 + 1] = l_run[r];
    }
}

// ---------------- E: merge K-split partials ----------------
__global__ __launch_bounds__(256) void k_merge(const unsigned short* __restrict__ pOn,
                                               const float* __restrict__ pML,
                                               float* __restrict__ out) {
  int idx = blockIdx.x * 256 + threadIdx.x;  // 524288
  int row = idx >> 6, d = idx & 63;
  float ms[NSPLIT], ls[NSPLIT];
  float M = -1e30f;
#pragma unroll
  for (int s = 0; s < NSPLIT; ++s) {
    ms[s] = pML[((size_t)s * SLEN + row) * 2 + 0];
    ls[s] = pML[((size_t)s * SLEN + row) * 2 + 1];
    M = fmaxf(M, ms[s]);
  }
  float Wsum = 0.f, O = 0.f;
#pragma unroll
  for (int s = 0; s < NSPLIT; ++s) {
    float w = ls[s] * exp2f(ms[s] - M);
    O += w * bf2f(pOn[((size_t)s * SLEN + row) * 64 + d]);
    Wsum += w;
  }
  out[idx] = O / Wsum;
}

extern "C" void kernel_launch(void* const* d_in, const int* in_sizes, int n_in,
                              void* d_out, int out_size, void* d_ws, size_t ws_size,
                              hipStream_t stream) {
  const float* x  = (const float*)d_in[0];
  const float* Wq = (const float*)d_in[1];
  const float* Wk = (const float*)d_in[2];
  const float* Wv = (const float*)d_in[3];
  float* out = (float*)d_out;

  char* w = (char*)d_ws;
  float* pQKV = (float*)w;                                   // 2*8192*192*4 = 12.58 MB
  unsigned short* Qh  = (unsigned short*)(w + (size_t)2 * SLEN * 192 * 4);
  unsigned short* Ql  = Qh + SLEN * 64;                      // 1.05 MB each
  unsigned short* Kh  = Ql + SLEN * 64;
  unsigned short* Kl  = Kh + SLEN * 64;
  unsigned short* Vt  = Kl + SLEN * 64;
  unsigned short* Wth = Vt + SLEN * 64;                      // 192*512 each
  unsigned short* Wtl = Wth + 192 * DIN;
  // pOn/pML alias pQKV (consumed by finqk/finv before k_flash writes)
  unsigned short* pOn = (unsigned short*)w;                  // 8*8192*64 bf16 = 8.39 MB
  float* pML = (float*)(w + (size_t)NSPLIT * SLEN * 64 * 2); // 8*8192*2 f32 = 0.52 MB

  k_splitw<<<dim3(384), dim3(256), 0, stream>>>(Wq, Wk, Wv, Wth, Wtl);
  k_qkv<<<dim3(128, 2, 2), dim3(256), 0, stream>>>(x, Wth, Wtl, pQKV);
  k_finqk<<<dim3(4096), dim3(256), 0, stream>>>(pQKV, Qh, Ql, Kh, Kl);
  k_finv<<<dim3(128), dim3(256), 0, stream>>>(pQKV, Vt);
  k_flash<<<dim3(128, NSPLIT), dim3(256), 0, stream>>>(Qh, Ql, Kh, Kl, Vt, pOn, pML);
  k_merge<<<dim3(2048), dim3(256), 0, stream>>>(pOn, pML, out);
}

// Round 4
// 99.029 us; speedup vs baseline: 1.4302x; 1.1789x over previous
//
#include <hip/hip_runtime.h>

#define SLEN 8192
#define DIN  512

typedef short bf16x8 __attribute__((ext_vector_type(8)));
typedef float f32x4  __attribute__((ext_vector_type(4)));
typedef float f32x16 __attribute__((ext_vector_type(16)));
typedef unsigned int u32x4 __attribute__((ext_vector_type(4)));
typedef unsigned int u32x2 __attribute__((ext_vector_type(2)));

__device__ __forceinline__ unsigned short f2bf(float f) {
  unsigned int u = __float_as_uint(f);
  u += 0x7FFFu + ((u >> 16) & 1u);           // RNE
  return (unsigned short)(u >> 16);
}
__device__ __forceinline__ float bf2f(unsigned short h) {
  return __uint_as_float(((unsigned int)h) << 16);
}
__device__ __forceinline__ unsigned int cvtpk(float lo, float hi) {
  unsigned int r;
  asm volatile("v_cvt_pk_bf16_f32 %0, %1, %2" : "=v"(r) : "v"(lo), "v"(hi));
  return r;
}

#define MFMA16(a, b, c) __builtin_amdgcn_mfma_f32_16x16x32_bf16((a), (b), (c), 0, 0, 0)
#define MFMA32(a, b, c) __builtin_amdgcn_mfma_f32_32x32x16_bf16((a), (b), (c), 0, 0, 0)

// XOR swizzle for [row][128B] LDS tiles
__device__ __forceinline__ int SW(int row, int off) {
  return row * 128 + (off ^ ((row & 7) << 4));
}

// ------- B: split + transpose W -> Wt[n][k], n: 0-63 Q(scaled), 64-127 K, 128-191 V -------
__global__ __launch_bounds__(256) void k_splitw(const float* __restrict__ Wq,
                                                const float* __restrict__ Wk,
                                                const float* __restrict__ Wv,
                                                unsigned short* __restrict__ Wth,
                                                unsigned short* __restrict__ Wtl) {
  int idx = blockIdx.x * 256 + threadIdx.x;  // n*512 + k, 98304 total
  int n = idx >> 9, k = idx & 511;
  float w;
  if (n < 64)       w = Wq[k * 64 + n] * 0.18033688011112042f;  // log2(e)/8 folded in
  else if (n < 128) w = Wk[k * 64 + (n - 64)];
  else              w = Wv[k * 64 + (n - 128)];
  unsigned short h = f2bf(w);
  Wth[idx] = h;
  Wtl[idx] = f2bf(w - bf2f(h));
}

// ---------------- C: QKV = x @ [Wq|Wk|Wv], fused epilogue (no partials) ----------------
__global__ __launch_bounds__(256) void k_qkv(const float* __restrict__ x,
                                             const unsigned short* __restrict__ Wth,
                                             const unsigned short* __restrict__ Wtl,
                                             unsigned short* __restrict__ Qh,
                                             unsigned short* __restrict__ Ql,
                                             unsigned short* __restrict__ Kh,
                                             unsigned short* __restrict__ Kl,
                                             unsigned short* __restrict__ Vt) {
  const int tid = threadIdx.x;
  const int wave = tid >> 6, lane = tid & 63;
  const int c = lane & 15, g = lane >> 4;
  const int wm = wave >> 1, wn = wave & 1;
  const int mbase = blockIdx.x * 32;              // 256 m-blocks of 32 rows
  const int nt0 = blockIdx.y * 6 + wn * 3;        // 12 n-tiles of 16

  const int rowA = mbase + wm * 16 + c;
  f32x4 acc[3];
  for (int j = 0; j < 3; ++j) acc[j] = (f32x4){0.f, 0.f, 0.f, 0.f};

  for (int k0 = 0; k0 < DIN; k0 += 32) {
    const float* xp = x + (size_t)rowA * DIN + k0 + g * 8;
    float4 f0 = *reinterpret_cast<const float4*>(xp);
    float4 f1 = *reinterpret_cast<const float4*>(xp + 4);
    float fv[8] = {f0.x, f0.y, f0.z, f0.w, f1.x, f1.y, f1.z, f1.w};
    bf16x8 ah, al;
#pragma unroll
    for (int j = 0; j < 8; ++j) {
      unsigned short h = f2bf(fv[j]);
      ah[j] = (short)h;
      al[j] = (short)f2bf(fv[j] - bf2f(h));
    }
#pragma unroll
    for (int j = 0; j < 3; ++j) {
      int ncol = (nt0 + j) * 16 + c;
      bf16x8 bh = *reinterpret_cast<const bf16x8*>(&Wth[ncol * DIN + k0 + g * 8]);
      bf16x8 bl = *reinterpret_cast<const bf16x8*>(&Wtl[ncol * DIN + k0 + g * 8]);
      acc[j] = MFMA16(ah, bh, acc[j]);
      acc[j] = MFMA16(ah, bl, acc[j]);
      acc[j] = MFMA16(al, bh, acc[j]);
    }
  }
  // C layout: col=lane&15, row=(lane>>4)*4+r
#pragma unroll
  for (int j = 0; j < 3; ++j) {
    int nt = nt0 + j;
    if (nt < 8) {
#pragma unroll
      for (int r = 0; r < 4; ++r) {
        int Rrow = mbase + wm * 16 + g * 4 + r;
        float v = acc[j][r];
        unsigned short h = f2bf(v);
        unsigned short lo = f2bf(v - bf2f(h));
        if (nt < 4) {
          Qh[Rrow * 64 + nt * 16 + c] = h;
          Ql[Rrow * 64 + nt * 16 + c] = lo;
        } else {
          Kh[Rrow * 64 + (nt - 4) * 16 + c] = h;
          Kl[Rrow * 64 + (nt - 4) * 16 + c] = lo;
        }
      }
    } else {
      int np = nt * 16 + c - 128;
      int Rbase = mbase + wm * 16 + g * 4;
      u32x2 pk;
      pk.x = cvtpk(acc[j][0], acc[j][1]);
      pk.y = cvtpk(acc[j][2], acc[j][3]);
      *reinterpret_cast<u32x2*>(&Vt[(size_t)np * SLEN + Rbase]) = pk;  // V^T [64][8192]
    }
  }
}

// ---------------- D: flash attention, swapped 32x32 structure ----------------
template <int NS>
__global__ __launch_bounds__(256, 2) void k_flash(const unsigned short* __restrict__ Qh,
                                                  const unsigned short* __restrict__ Ql,
                                                  const unsigned short* __restrict__ Kh,
                                                  const unsigned short* __restrict__ Kl,
                                                  const unsigned short* __restrict__ Vt,
                                                  unsigned short* __restrict__ pOn,
                                                  float* __restrict__ pML) {
  constexpr int KIT = 128 / NS;   // 64-key tiles per split
  __shared__ __align__(16) unsigned char smem[3 * 8192];
  const int tid = threadIdx.x;
  const int wave = tid >> 6, lane = tid & 63;
  const int q32 = lane & 31, hi = lane >> 5;
  const int qtile = blockIdx.x;   // 32 q-tiles of 256
  const int ks = blockIdx.y;
  unsigned char* KH = smem;
  unsigned char* KL = smem + 8192;
  unsigned char* VT = smem + 16384;

  // Q B-fragments: B[k=hi*8+j][col=q32], per (qs, kk): bf16x8 of own q-row
  int qrow[2];
  bf16x8 qfh[2][4], qfl[2][4];
#pragma unroll
  for (int qs = 0; qs < 2; ++qs) {
    qrow[qs] = qtile * 256 + wave * 64 + qs * 32 + q32;
#pragma unroll
    for (int kk = 0; kk < 4; ++kk) {
      qfh[qs][kk] = *reinterpret_cast<const bf16x8*>(&Qh[qrow[qs] * 64 + kk * 16 + hi * 8]);
      qfl[qs][kk] = *reinterpret_cast<const bf16x8*>(&Ql[qrow[qs] * 64 + kk * 16 + hi * 8]);
    }
  }
  bf16x8 ones8;
#pragma unroll
  for (int j = 0; j < 8; ++j) ones8[j] = (short)0x3F80;

  f32x16 o[2][2];
#pragma unroll
  for (int qs = 0; qs < 2; ++qs)
#pragma unroll
    for (int db = 0; db < 2; ++db)
#pragma unroll
      for (int r = 0; r < 16; ++r) o[qs][db][r] = 0.f;
  float m_run[2] = {-1e30f, -1e30f};
  float l_run[2] = {0.f, 0.f};

  u32x4 st[6];
  auto LOADTILE = [&](int it) {
    const int kb = ks * (SLEN / NS) + it * 64;
#pragma unroll
    for (int u = 0; u < 6; ++u) {
      int unit = tid + u * 256;
      int idx = unit & 511, row = idx >> 3, seg = idx & 7;
      if (u < 2)      st[u] = *reinterpret_cast<const u32x4*>(&Kh[(kb + row) * 64 + seg * 8]);
      else if (u < 4) st[u] = *reinterpret_cast<const u32x4*>(&Kl[(kb + row) * 64 + seg * 8]);
      else            st[u] = *reinterpret_cast<const u32x4*>(&Vt[(size_t)row * SLEN + kb + seg * 8]);
    }
  };

  LOADTILE(0);
  for (int it = 0; it < KIT; ++it) {
    __syncthreads();
#pragma unroll
    for (int u = 0; u < 6; ++u) {
      int unit = tid + u * 256;
      int arr = unit >> 9, idx = unit & 511, row = idx >> 3, seg = idx & 7;
      *reinterpret_cast<u32x4*>(&smem[arr * 8192 + SW(row, seg * 16)]) = st[u];
    }
    __syncthreads();
    if (it + 1 < KIT) LOADTILE(it + 1);

#pragma unroll
    for (int s = 0; s < 2; ++s) {          // two 32-key subtiles
      bf16x8 kfh[4], kfl[4], vf[2][2];
#pragma unroll
      for (int kk = 0; kk < 4; ++kk) {
        kfh[kk] = *reinterpret_cast<const bf16x8*>(&KH[SW(32 * s + q32, 32 * kk + 16 * hi)]);
        kfl[kk] = *reinterpret_cast<const bf16x8*>(&KL[SW(32 * s + q32, 32 * kk + 16 * hi)]);
      }
#pragma unroll
      for (int db = 0; db < 2; ++db)
#pragma unroll
        for (int ch = 0; ch < 2; ++ch)
          vf[db][ch] = *reinterpret_cast<const bf16x8*>(&VT[SW(32 * db + q32, 64 * s + 32 * ch + 16 * hi)]);

#pragma unroll
      for (int qs = 0; qs < 2; ++qs) {
        // S^T = K·Q^T: D[k=crow(r,hi)][q=q32]
        f32x16 S;
#pragma unroll
        for (int r = 0; r < 16; ++r) S[r] = 0.f;
        __builtin_amdgcn_s_setprio(1);
#pragma unroll
        for (int kk = 0; kk < 4; ++kk) {
          S = MFMA32(kfh[kk], qfh[qs][kk], S);
          S = MFMA32(kfh[kk], qfl[qs][kk], S);
          S = MFMA32(kfl[kk], qfh[qs][kk], S);
        }
        __builtin_amdgcn_s_setprio(0);

        // lane-local row max (own 16 k) + cross-half combine
        float pm = S[0];
#pragma unroll
        for (int r = 1; r < 16; ++r) pm = fmaxf(pm, S[r]);
        pm = fmaxf(pm, __shfl_xor(pm, 32));
        if (!__all(pm - m_run[qs] <= 8.0f)) {   // defer-max (T13)
          float mnew = fmaxf(m_run[qs], pm);
          float alpha = exp2f(m_run[qs] - mnew);
#pragma unroll
          for (int db = 0; db < 2; ++db)
#pragma unroll
            for (int r = 0; r < 16; ++r) o[qs][db][r] *= alpha;
          l_run[qs] *= alpha;
          m_run[qs] = mnew;
        }
        float p[16];
#pragma unroll
        for (int r = 0; r < 16; ++r) p[r] = exp2f(S[r] - m_run[qs]);
        unsigned int W[8];
#pragma unroll
        for (int i = 0; i < 8; ++i) W[i] = cvtpk(p[2 * i], p[2 * i + 1]);
        // redistribute k-halves across lane halves -> PV B-fragments (T12)
        asm volatile("v_permlane32_swap_b32 %0, %1" : "+v"(W[0]), "+v"(W[2]));
        asm volatile("v_permlane32_swap_b32 %0, %1" : "+v"(W[1]), "+v"(W[3]));
        asm volatile("v_permlane32_swap_b32 %0, %1" : "+v"(W[4]), "+v"(W[6]));
        asm volatile("v_permlane32_swap_b32 %0, %1" : "+v"(W[5]), "+v"(W[7]));
        u32x4 pw0 = {W[0], W[1], W[2], W[3]};
        u32x4 pw1 = {W[4], W[5], W[6], W[7]};
        bf16x8 pb0 = *reinterpret_cast<bf16x8*>(&pw0);
        bf16x8 pb1 = *reinterpret_cast<bf16x8*>(&pw1);

        __builtin_amdgcn_s_setprio(1);
        f32x16 rs;
#pragma unroll
        for (int r = 0; r < 16; ++r) rs[r] = 0.f;
        rs = MFMA32(ones8, pb0, rs);            // rowsum[q] in every row
        rs = MFMA32(ones8, pb1, rs);
        // O^T[d][q] += V^T·P^T
        o[qs][0] = MFMA32(vf[0][0], pb0, o[qs][0]);
        o[qs][0] = MFMA32(vf[0][1], pb1, o[qs][0]);
        o[qs][1] = MFMA32(vf[1][0], pb0, o[qs][1]);
        o[qs][1] = MFMA32(vf[1][1], pb1, o[qs][1]);
        __builtin_amdgcn_s_setprio(0);
        l_run[qs] += rs[0];
      }
    }
  }

  // epilogue: normalized bf16 partials + (m,l)
#pragma unroll
  for (int qs = 0; qs < 2; ++qs) {
    float inv = 1.0f / l_run[qs];
#pragma unroll
    for (int db = 0; db < 2; ++db)
#pragma unroll
      for (int i = 0; i < 8; ++i) {
        unsigned int w = cvtpk(o[qs][db][2 * i] * inv, o[qs][db][2 * i + 1] * inv);
        int d = 2 * (i & 1) + 8 * (i >> 1) + 4 * hi + 32 * db;
        *reinterpret_cast<unsigned int*>(&pOn[((size_t)ks * SLEN + qrow[qs]) * 64 + d]) = w;
      }
    if (hi == 0) {
      pML[((size_t)ks * SLEN + qrow[qs]) * 2 + 0] = m_run[qs];
      pML[((size_t)ks * SLEN + qrow[qs]) * 2 + 1] = l_run[qs];
    }
  }
}

// ---------------- E: merge K-split partials ----------------
template <int NS>
__global__ __launch_bounds__(256) void k_merge(const unsigned short* __restrict__ pOn,
                                               const float* __restrict__ pML,
                                               float* __restrict__ out) {
  int idx = blockIdx.x * 256 + threadIdx.x;  // 524288
  int row = idx >> 6, d = idx & 63;
  float ms[NS], ls[NS];
  float M = -1e30f;
#pragma unroll
  for (int s = 0; s < NS; ++s) {
    ms[s] = pML[((size_t)s * SLEN + row) * 2 + 0];
    ls[s] = pML[((size_t)s * SLEN + row) * 2 + 1];
    M = fmaxf(M, ms[s]);
  }
  float Wsum = 0.f, O = 0.f;
#pragma unroll
  for (int s = 0; s < NS; ++s) {
    float w = ls[s] * exp2f(ms[s] - M);
    O += w * bf2f(pOn[((size_t)s * SLEN + row) * 64 + d]);
    Wsum += w;
  }
  out[idx] = O / Wsum;
}

extern "C" void kernel_launch(void* const* d_in, const int* in_sizes, int n_in,
                              void* d_out, int out_size, void* d_ws, size_t ws_size,
                              hipStream_t stream) {
  const float* x  = (const float*)d_in[0];
  const float* Wq = (const float*)d_in[1];
  const float* Wk = (const float*)d_in[2];
  const float* Wv = (const float*)d_in[3];
  float* out = (float*)d_out;

  char* w = (char*)d_ws;
  const size_t QB = (size_t)SLEN * 64 * 2;       // 1,048,576 per buffer
  unsigned short* Qh = (unsigned short*)w;
  unsigned short* Ql = Qh + SLEN * 64;
  unsigned short* Kh = Ql + SLEN * 64;
  unsigned short* Kl = Kh + SLEN * 64;
  unsigned short* Vt = Kl + SLEN * 64;
  char* tail = w + 5 * QB;                       // 5,242,880
  // W lives in [tail, tail+393216): dead once k_qkv finishes; pML overlays it later
  unsigned short* Wth = (unsigned short*)tail;
  unsigned short* Wtl = Wth + 192 * DIN;

  k_splitw<<<dim3(384), dim3(256), 0, stream>>>(Wq, Wk, Wv, Wth, Wtl);
  k_qkv<<<dim3(256, 2), dim3(256), 0, stream>>>(x, Wth, Wtl, Qh, Ql, Kh, Kl, Vt);

  const size_t need16 = 5 * QB + 16 * (size_t)SLEN * 8 + 16 * (size_t)SLEN * 64 * 2;
  if (ws_size >= need16) {
    float* pML = (float*)tail;                                   // 16*8192*2 f32 = 1 MB
    unsigned short* pOn = (unsigned short*)(tail + 16 * (size_t)SLEN * 8);
    k_flash<16><<<dim3(32, 16), dim3(256), 0, stream>>>(Qh, Ql, Kh, Kl, Vt, pOn, pML);
    k_merge<16><<<dim3(2048), dim3(256), 0, stream>>>(pOn, pML, out);
  } else {
    float* pML = (float*)tail;                                   // 8*8192*2 f32 = 0.5 MB
    unsigned short* pOn = (unsigned short*)(tail + 8 * (size_t)SLEN * 8);
    k_flash<8><<<dim3(32, 8), dim3(256), 0, stream>>>(Qh, Ql, Kh, Kl, Vt, pOn, pML);
    k_merge<8><<<dim3(2048), dim3(256), 0, stream>>>(pOn, pML, out);
  }
}